// Round 8
// baseline (294.173 us; speedup 1.0000x reference)
//
#include <hip/hip_runtime.h>
#include <math.h>

#define HDIM 256
#define FDIM 768
#define BM 128
#define BK 32

typedef __attribute__((ext_vector_type(8))) short short8;
typedef __attribute__((ext_vector_type(4))) float f32x4;
typedef __attribute__((ext_vector_type(4))) unsigned short us4;

__device__ __forceinline__ unsigned short f2bf(float f) {
  unsigned int u = __float_as_uint(f);
  unsigned int r = (u + 0x7FFFu + ((u >> 16) & 1u)) >> 16;
  return (unsigned short)r;
}
__device__ __forceinline__ float bf2f(unsigned short b) {
  return __uint_as_float(((unsigned int)b) << 16);
}

__device__ __forceinline__ void gload_lds16(const void* g, void* l) {
  __builtin_amdgcn_global_load_lds(
      (const __attribute__((address_space(1))) void*)g,
      (__attribute__((address_space(3))) void*)l, 16, 0, 0);
}

// ---------------- prep: compute_v + cvtW1 + cvtW2 + hist, one dispatch ----------------

__global__ __launch_bounds__(256) void k_prep(
    const float* __restrict__ We1, const float* __restrict__ ae1,
    const float* __restrict__ We2, const float* __restrict__ ae2,
    float* __restrict__ v1, float* __restrict__ v2,
    const float* __restrict__ W1, unsigned short* __restrict__ W1t,
    const float* __restrict__ W2, unsigned short* __restrict__ W2t,
    const int* __restrict__ dstArr, int* __restrict__ cnt, int E) {
  int bid = blockIdx.x;
  if (bid < 384) {
    int row = bid * 4 + (threadIdx.x >> 6);
    int lane = threadIdx.x & 63;
    const float* W = (row < FDIM) ? We1 : We2;
    const float* a = (row < FDIM) ? ae1 : ae2;
    int r = (row < FDIM) ? row : row - FDIM;
    float4 w = *(const float4*)&W[(size_t)r * HDIM + lane * 4];
    float4 av = *(const float4*)&a[lane * 4];
    float p = w.x * av.x + w.y * av.y + w.z * av.z + w.w * av.w;
    #pragma unroll
    for (int off = 32; off; off >>= 1) p += __shfl_down(p, off, 64);
    if (lane == 0) ((row < FDIM) ? v1 : v2)[r] = p;
  } else if (bid < 640) {
    int nn = bid - 384;
    for (int k = threadIdx.x; k < FDIM; k += 256)
      W1t[(size_t)nn * FDIM + k] = f2bf(W1[(size_t)k * HDIM + nn]);
  } else if (bid < 896) {
    int nn = bid - 640;
    for (int k = threadIdx.x; k < HDIM; k += 256)
      W2t[(size_t)nn * HDIM + k] = f2bf(W2[(size_t)k * HDIM + nn]);
  } else {
    int e = (bid - 896) * 256 + threadIdx.x;
    if (e < E) atomicAdd(&cnt[dstArr[e]], 1);
  }
}

// ---------------- single-dispatch CSR scan (decoupled lookback) ----------------
// nb = (n+255)/256 <= 256 blocks -> all co-resident; block b waits only on
// lower-ID blocks' published aggregates (deadlock-free). flags pre-zeroed.

__global__ __launch_bounds__(256) void k_scan_lb(const int* __restrict__ cnt,
                                                 int* __restrict__ offsets,
                                                 int* __restrict__ cursor,
                                                 int* __restrict__ bsums,
                                                 int* __restrict__ flags, int n) {
  __shared__ int s[256];
  __shared__ int r[256];
  const int b = blockIdx.x, t = threadIdx.x;
  int i = b * 256 + t;
  int v = (i < n) ? cnt[i] : 0;
  s[t] = v;
  __syncthreads();
  for (int off = 1; off < 256; off <<= 1) {
    int tv = (t >= off) ? s[t - off] : 0;
    __syncthreads();
    s[t] += tv;
    __syncthreads();
  }
  if (t == 255) {
    bsums[b] = s[255];
    __threadfence();
    __hip_atomic_store(&flags[b], 1, __ATOMIC_RELEASE, __HIP_MEMORY_SCOPE_AGENT);
  }
  int contrib = 0;
  if (t < b) {
    while (!__hip_atomic_load(&flags[t], __ATOMIC_ACQUIRE, __HIP_MEMORY_SCOPE_AGENT))
      __builtin_amdgcn_s_sleep(2);
    contrib = bsums[t];
  }
  r[t] = contrib;
  __syncthreads();
  #pragma unroll
  for (int off = 128; off; off >>= 1) {
    if (t < off) r[t] += r[t + off];
    __syncthreads();
  }
  int base = r[0];
  if (i < n) {
    int incl = base + s[t];
    offsets[i + 1] = incl;
    cursor[i] = incl - v;
    if (i == 0) offsets[0] = 0;
  }
}

// ---------------- GEMM body: C[M][HDIM] = A@Bt^T, fused row-dots ----------------

template <bool AF32, bool COUTBF>
__device__ __forceinline__ void gemm_body(unsigned char* lds,
                                          const void* __restrict__ Ain,
                                          const unsigned short* __restrict__ Bt,
                                          void* __restrict__ Cout,
                                          float* __restrict__ sOut,
                                          float* __restrict__ dOut,
                                          const float* __restrict__ a_src,
                                          const float* __restrict__ a_dst,
                                          int M, int K, int tile) {
  unsigned char* As = lds;
  unsigned char* Bs = lds + 8192;
  float* partS = (float*)(lds + 24576);         // [4][128]
  float* partD = (float*)(lds + 24576 + 2048);  // [4][128]
  const int t = threadIdx.x;
  const int l = t & 63;
  const int w = t >> 6;
  const int wm = w >> 2, wn = w & 3;
  const int bm = tile * BM;

  f32x4 acc[4][4] = {};

  int rowA = bm + (t & 127);
  if (rowA >= M) rowA = M - 1;
  const int cA = t >> 7;
  int rowAr = bm + (t >> 2);
  if (rowAr >= M) rowAr = M - 1;
  const int kbAr = t & 3;
  const int sAr = kbAr * 2048 + (t >> 2) * 16;
  const int nB = t & 255;
  const int cB0 = t >> 8;
  const int cB1 = 2 + (t >> 8);

  int aAddr[4], bAddr[4];
  #pragma unroll
  for (int mt = 0; mt < 4; ++mt) {
    int m = wm * 64 + mt * 16 + (l & 15);
    aAddr[mt] = (l >> 4) * 2048 + m * 16;
  }
  #pragma unroll
  for (int nt = 0; nt < 4; ++nt) {
    int nn = wn * 64 + nt * 16 + (l & 15);
    bAddr[nt] = (l >> 4) * 4096 + nn * 16;
  }

  const int nsteps = K / BK;
  for (int ks = 0; ks < nsteps; ++ks) {
    const int k0 = ks * BK;
    __syncthreads();
    if (AF32) {
      const float* A = (const float*)Ain;
      const float* p = A + (size_t)rowAr * K + k0 + kbAr * 8;
      float4 f0 = *(const float4*)p;
      float4 f1 = *(const float4*)(p + 4);
      short8 hv;
      hv[0] = (short)f2bf(f0.x); hv[1] = (short)f2bf(f0.y);
      hv[2] = (short)f2bf(f0.z); hv[3] = (short)f2bf(f0.w);
      hv[4] = (short)f2bf(f1.x); hv[5] = (short)f2bf(f1.y);
      hv[6] = (short)f2bf(f1.z); hv[7] = (short)f2bf(f1.w);
      *(short8*)(As + sAr) = hv;
    } else {
      const unsigned short* A = (const unsigned short*)Ain;
      gload_lds16(A + (size_t)rowA * K + k0 + cA * 8, As + t * 16);
    }
    gload_lds16(Bt + (size_t)nB * K + k0 + cB0 * 8, Bs + t * 16);
    gload_lds16(Bt + (size_t)nB * K + k0 + cB1 * 8, Bs + 8192 + t * 16);
    __syncthreads();

    short8 af[4], bfr[4];
    #pragma unroll
    for (int mt = 0; mt < 4; ++mt) af[mt] = *(const short8*)(As + aAddr[mt]);
    #pragma unroll
    for (int nt = 0; nt < 4; ++nt) bfr[nt] = *(const short8*)(Bs + bAddr[nt]);
    #pragma unroll
    for (int mt = 0; mt < 4; ++mt)
      #pragma unroll
      for (int nt = 0; nt < 4; ++nt)
        acc[mt][nt] = __builtin_amdgcn_mfma_f32_16x16x32_bf16(af[mt], bfr[nt], acc[mt][nt], 0, 0, 0);
  }

  float asv[4], adv[4];
  #pragma unroll
  for (int nt = 0; nt < 4; ++nt) {
    int col = wn * 64 + nt * 16 + (l & 15);
    asv[nt] = a_src[col];
    adv[nt] = a_dst[col];
  }
  #pragma unroll
  for (int mt = 0; mt < 4; ++mt) {
    int rloc = wm * 64 + mt * 16 + ((l >> 4) << 2);
    #pragma unroll
    for (int r = 0; r < 4; ++r) {
      int row = bm + rloc + r;
      float ps = 0.f, pd = 0.f;
      #pragma unroll
      for (int nt = 0; nt < 4; ++nt) {
        float v = acc[mt][nt][r];
        if (row < M) {
          int col = wn * 64 + nt * 16 + (l & 15);
          if (COUTBF)
            ((unsigned short*)Cout)[(size_t)row * HDIM + col] = f2bf(v);
          else
            ((float*)Cout)[(size_t)row * HDIM + col] = v;
        }
        ps += v * asv[nt];
        pd += v * adv[nt];
      }
      #pragma unroll
      for (int off = 1; off < 16; off <<= 1) {
        ps += __shfl_xor(ps, off, 64);
        pd += __shfl_xor(pd, off, 64);
      }
      if ((l & 15) == 0) {
        partS[wn * 128 + rloc + r] = ps;
        partD[wn * 128 + rloc + r] = pd;
      }
    }
  }
  __syncthreads();
  if (t < 128) {
    int row = bm + t;
    if (row < M) {
      sOut[row] = partS[t] + partS[128 + t] + partS[256 + t] + partS[384 + t];
      dOut[row] = partD[t] + partD[128 + t] + partD[256 + t] + partD[384 + t];
    }
  }
}

// ---------------- edge-alpha body (8 edges per 512-thread block) ----------------

__device__ __forceinline__ void edge_body(unsigned char* lds,
                                          const float* __restrict__ ea,
                                          const float* __restrict__ v1,
                                          const float* __restrict__ v2,
                                          float* __restrict__ o1,
                                          float* __restrict__ o2, int E, int ebid) {
  float* sv1 = (float*)lds;
  float* sv2 = (float*)(lds + 3072);
  for (int i = threadIdx.x; i < FDIM; i += 512) { sv1[i] = v1[i]; sv2[i] = v2[i]; }
  __syncthreads();
  int e = ebid * 8 + (threadIdx.x >> 6);
  if (e >= E) return;
  int lane = threadIdx.x & 63;
  const float* row = ea + (size_t)e * FDIM;
  float p1 = 0.f, p2 = 0.f;
  #pragma unroll
  for (int t = 0; t < 3; ++t) {
    int idx = t * 256 + lane * 4;
    float4 x = *(const float4*)&row[idx];
    float4 a = *(const float4*)&sv1[idx];
    float4 b = *(const float4*)&sv2[idx];
    p1 += x.x * a.x + x.y * a.y + x.z * a.z + x.w * a.w;
    p2 += x.x * b.x + x.y * b.y + x.z * b.z + x.w * b.w;
  }
  #pragma unroll
  for (int off = 32; off; off >>= 1) {
    p1 += __shfl_down(p1, off, 64);
    p2 += __shfl_down(p2, off, 64);
  }
  if (lane == 0) { o1[e] = p1; o2[e] = p2; }
}

// ---------------- fat kernel 1: GEMM1 || scatter || edge-alpha ----------------

#define NSCAT 98

__global__ __launch_bounds__(512) void k_fat1(
    const float* __restrict__ x, const unsigned short* __restrict__ W1t,
    unsigned short* __restrict__ xl1b, float* __restrict__ sArr, float* __restrict__ dArr,
    const float* __restrict__ as1, const float* __restrict__ ad1, int M,
    const float* __restrict__ ea, const float* __restrict__ v1,
    const float* __restrict__ v2, float* __restrict__ ae1Arr,
    float* __restrict__ ae2Arr, int E, int nGemm,
    const int* __restrict__ dstArr, int* __restrict__ cursor,
    int* __restrict__ elist) {
  __shared__ unsigned char lds[28672];
  int bid = blockIdx.x;
  if (bid < nGemm) {
    gemm_body<true, true>(lds, x, W1t, xl1b, sArr, dArr, as1, ad1, M, FDIM, bid);
  } else if (bid < nGemm + NSCAT) {
    int sb = bid - nGemm;
    for (int e = sb * 512 + threadIdx.x; e < E; e += NSCAT * 512) {
      int p = atomicAdd(&cursor[dstArr[e]], 1);
      elist[p] = e;
    }
  } else {
    edge_body(lds, ea, v1, v2, ae1Arr, ae2Arr, E, bid - nGemm - NSCAT);
  }
}

__global__ __launch_bounds__(512) void k_gemm2(
    const unsigned short* __restrict__ hb, const unsigned short* __restrict__ W2t,
    unsigned short* __restrict__ xl2b, float* __restrict__ sArr, float* __restrict__ dArr,
    const float* __restrict__ as2, const float* __restrict__ ad2, int M) {
  __shared__ unsigned char lds[28672];
  gemm_body<false, true>(lds, hb, W2t, xl2b, sArr, dArr, as2, ad2, M, HDIM, blockIdx.x);
}

// ---------------- shared per-node aggregation body (one wave, online softmax) ----------------

__device__ __forceinline__ void agg_node(const unsigned short* __restrict__ xlb,
                                         const float* __restrict__ sArr,
                                         float dnode,
                                         const float* __restrict__ aeArr,
                                         const int* __restrict__ src,
                                         const int* __restrict__ elist,
                                         int beg, int end, int lane,
                                         float& a0, float& a1, float& a2, float& a3) {
  float run_m = -1e30f, run_den = 0.f;
  a0 = a1 = a2 = a3 = 0.f;
  for (int c0 = beg; c0 < end; c0 += 64) {
    int j = c0 + lane;
    float al = -1e30f;
    int sj = 0;
    if (j < end) {
      int e = elist[j];
      sj = src[e];
      float a = sArr[sj] + dnode + aeArr[e];
      al = (a > 0.f) ? a : 0.2f * a;
    }
    float cm = al;
    #pragma unroll
    for (int off = 32; off; off >>= 1) cm = fmaxf(cm, __shfl_xor(cm, off, 64));
    float new_m = fmaxf(run_m, cm);
    float ev = (j < end) ? expf(al - new_m) : 0.f;
    float csum = ev;
    #pragma unroll
    for (int off = 32; off; off >>= 1) csum += __shfl_xor(csum, off, 64);
    float scale = expf(run_m - new_m);
    run_den = run_den * scale + csum;
    a0 *= scale; a1 *= scale; a2 *= scale; a3 *= scale;
    int cdeg = end - c0;
    if (cdeg > 64) cdeg = 64;
    for (int q = 0; q < cdeg; ++q) {
      float wgt = __shfl(ev, q, 64);
      int sq = __shfl(sj, q, 64);
      us4 v = *(const us4*)(xlb + (size_t)sq * HDIM + lane * 4);
      a0 += wgt * bf2f(v[0]); a1 += wgt * bf2f(v[1]);
      a2 += wgt * bf2f(v[2]); a3 += wgt * bf2f(v[3]);
    }
    run_m = new_m;
  }
  float inv = (end > beg) ? 1.f / run_den : 0.f;
  a0 *= inv; a1 *= inv; a2 *= inv; a3 *= inv;
}

// ---------------- layer-1 aggregate (all nodes, relu, bf16 out) ----------------

__global__ __launch_bounds__(256) void k_aggregate1(const unsigned short* __restrict__ xlb,
                                                    const float* __restrict__ sArr,
                                                    const float* __restrict__ dArr,
                                                    const float* __restrict__ aeArr,
                                                    const int* __restrict__ src,
                                                    const int* __restrict__ offsets,
                                                    const int* __restrict__ elist,
                                                    const float* __restrict__ bias,
                                                    unsigned short* __restrict__ outb,
                                                    int n) {
  int node = blockIdx.x * 4 + (threadIdx.x >> 6);
  if (node >= n) return;
  int lane = threadIdx.x & 63;
  int beg = offsets[node], end = offsets[node + 1];
  float a0, a1, a2, a3;
  agg_node(xlb, sArr, dArr[node], aeArr, src, elist, beg, end, lane, a0, a1, a2, a3);
  float4 bv = *(const float4*)(bias + lane * 4);
  float o0 = fmaxf(a0 + bv.x, 0.f), o1 = fmaxf(a1 + bv.y, 0.f);
  float o2 = fmaxf(a2 + bv.z, 0.f), o3 = fmaxf(a3 + bv.w, 0.f);
  us4 ov;
  ov[0] = f2bf(o0); ov[1] = f2bf(o1); ov[2] = f2bf(o2); ov[3] = f2bf(o3);
  *(us4*)(outb + (size_t)node * HDIM + lane * 4) = ov;
}

// ---------------- fused layer-2 aggregate (pair nodes only) + head ----------------

__global__ __launch_bounds__(256) void k_agg2head(const unsigned short* __restrict__ xl2b,
                                                  const float* __restrict__ sArr,
                                                  const float* __restrict__ dArr,
                                                  const float* __restrict__ aeArr,
                                                  const int* __restrict__ src,
                                                  const int* __restrict__ offsets,
                                                  const int* __restrict__ elist,
                                                  const float* __restrict__ b2,
                                                  const int* __restrict__ nodes,
                                                  const float* __restrict__ Wp,
                                                  const float* __restrict__ bp,
                                                  float* __restrict__ out, int Bn) {
  __shared__ float tls[2][2][HDIM];
  int wv = threadIdx.x >> 6;
  int lane = threadIdx.x & 63;
  int pl = wv >> 1;
  int side = wv & 1;
  int b = blockIdx.x * 2 + pl;
  if (b < Bn) {
    int node = nodes[side * Bn + b];
    int beg = offsets[node], end = offsets[node + 1];
    float a0, a1, a2, a3;
    agg_node(xl2b, sArr, dArr[node], aeArr, src, elist, beg, end, lane, a0, a1, a2, a3);
    float4 bv = *(const float4*)(b2 + lane * 4);
    float* dstp = &tls[pl][side][lane * 4];
    dstp[0] = a0 + bv.x; dstp[1] = a1 + bv.y;
    dstp[2] = a2 + bv.z; dstp[3] = a3 + bv.w;
  }
  __syncthreads();
  if (b < Bn && side == 0) {
    float4 t0 = *(const float4*)&tls[pl][0][lane * 4];
    float4 t1 = *(const float4*)&tls[pl][1][lane * 4];
    float c0 = t0.x * t1.x, c1 = t0.y * t1.y, c2 = t0.z * t1.z, c3 = t0.w * t1.w;
    int h0 = lane * 4;
    float s0 = c0 * Wp[h0 * 3 + 0] + c1 * Wp[(h0 + 1) * 3 + 0] +
               c2 * Wp[(h0 + 2) * 3 + 0] + c3 * Wp[(h0 + 3) * 3 + 0];
    float s1 = c0 * Wp[h0 * 3 + 1] + c1 * Wp[(h0 + 1) * 3 + 1] +
               c2 * Wp[(h0 + 2) * 3 + 1] + c3 * Wp[(h0 + 3) * 3 + 1];
    float s2 = c0 * Wp[h0 * 3 + 2] + c1 * Wp[(h0 + 1) * 3 + 2] +
               c2 * Wp[(h0 + 2) * 3 + 2] + c3 * Wp[(h0 + 3) * 3 + 2];
    #pragma unroll
    for (int off = 32; off; off >>= 1) {
      s0 += __shfl_down(s0, off, 64);
      s1 += __shfl_down(s1, off, 64);
      s2 += __shfl_down(s2, off, 64);
    }
    if (lane == 0) {
      out[b * 3 + 0] = s0 + bp[0];
      out[b * 3 + 1] = s1 + bp[1];
      out[b * 3 + 2] = s2 + bp[2];
    }
  }
}

// ---------------- launch ----------------

extern "C" void kernel_launch(void* const* d_in, const int* in_sizes, int n_in,
                              void* d_out, int out_size, void* d_ws, size_t ws_size,
                              hipStream_t stream) {
  const float* x         = (const float*)d_in[0];
  const float* edge_attr = (const float*)d_in[1];
  const float* W1  = (const float*)d_in[2];
  const float* as1 = (const float*)d_in[3];
  const float* ad1 = (const float*)d_in[4];
  const float* We1 = (const float*)d_in[5];
  const float* ae1 = (const float*)d_in[6];
  const float* b1  = (const float*)d_in[7];
  const float* W2  = (const float*)d_in[8];
  const float* as2 = (const float*)d_in[9];
  const float* ad2 = (const float*)d_in[10];
  const float* We2 = (const float*)d_in[11];
  const float* ae2 = (const float*)d_in[12];
  const float* b2  = (const float*)d_in[13];
  const float* Wp  = (const float*)d_in[14];
  const float* bp  = (const float*)d_in[15];
  const int* edge_index = (const int*)d_in[16];
  const int* nodes      = (const int*)d_in[17];

  const int N  = in_sizes[0] / FDIM;
  const int E  = in_sizes[16] / 2;
  const int Bn = in_sizes[17] / 2;
  const int* srcArr = edge_index;
  const int* dstArr = edge_index + E;

  char* w = (char*)d_ws;
  auto carve = [&](size_t bytes) -> void* {
    void* p = (void*)w;
    w += (bytes + 255) & ~(size_t)255;
    return p;
  };
  unsigned short* xl1b   = (unsigned short*)carve(2 * (size_t)N * HDIM);  // also xl2b
  unsigned short* hb     = (unsigned short*)carve(2 * (size_t)N * HDIM);
  unsigned short* W1t    = (unsigned short*)carve(2 * (size_t)FDIM * HDIM);
  unsigned short* W2t    = (unsigned short*)carve(2 * (size_t)HDIM * HDIM);
  float* ae1Arr = (float*)carve(sizeof(float) * E);
  float* ae2Arr = (float*)carve(sizeof(float) * E);
  float* sArr = (float*)carve(sizeof(float) * N);
  float* dArr = (float*)carve(sizeof(float) * N);
  float* v1 = (float*)carve(sizeof(float) * FDIM);
  float* v2 = (float*)carve(sizeof(float) * FDIM);
  int* cntflags = (int*)carve(sizeof(int) * (N + 256));  // cnt[N] + flags[256], one memset
  int* offsets = (int*)carve(sizeof(int) * (N + 1));
  int* cursor  = (int*)carve(sizeof(int) * N);
  int* elist   = (int*)carve(sizeof(int) * E);
  int* bsums   = (int*)carve(sizeof(int) * 256);

  int* cnt = cntflags;
  int* flags = cntflags + N;

  const int nbScan = (N + 255) / 256;
  const int nbHist = (E + 255) / 256;
  const int nGemm = (N + BM - 1) / BM;
  const int nEdge = (E + 7) / 8;

  // zero cnt + lookback flags (one memset)
  hipMemsetAsync(cntflags, 0, sizeof(int) * (N + 256), stream);
  // prep: compute_v + weight cvt + hist
  k_prep<<<896 + nbHist, 256, 0, stream>>>(We1, ae1, We2, ae2, v1, v2,
                                           W1, W1t, W2, W2t, dstArr, cnt, E);
  // single-dispatch scan (offsets + cursor)
  k_scan_lb<<<nbScan, 256, 0, stream>>>(cnt, offsets, cursor, bsums, flags, N);

  // fat: GEMM1 (+row-dots, bf16 C) || scatter || edge-alpha (both layers)
  k_fat1<<<nGemm + NSCAT + nEdge, 512, 0, stream>>>(
      x, W1t, xl1b, sArr, dArr, as1, ad1, N,
      edge_attr, v1, v2, ae1Arr, ae2Arr, E, nGemm, dstArr, cursor, elist);
  // layer 1 aggregate (bf16 gather) -> hb (bf16)
  k_aggregate1<<<(N + 3) / 4, 256, 0, stream>>>(xl1b, sArr, dArr, ae1Arr, srcArr,
                                                offsets, elist, b1, hb, N);
  // layer 2 GEMM (xl2 bf16, aliases xl1b buffer)
  k_gemm2<<<nGemm, 512, 0, stream>>>(hb, W2t, xl1b, sArr, dArr, as2, ad2, N);
  // fused layer-2 aggregate (pair nodes only) + head
  k_agg2head<<<(Bn + 1) / 2, 256, 0, stream>>>(xl1b, sArr, dArr, ae2Arr, srcArr,
                                               offsets, elist, b2, nodes, Wp, bp,
                                               (float*)d_out, Bn);
}

// Round 9
// 275.974 us; speedup vs baseline: 1.0659x; 1.0659x over previous
//
#include <hip/hip_runtime.h>
#include <math.h>

#define HDIM 256
#define FDIM 768
#define BM 128
#define BK 32

typedef __attribute__((ext_vector_type(8))) short short8;
typedef __attribute__((ext_vector_type(4))) float f32x4;
typedef __attribute__((ext_vector_type(4))) unsigned short us4;

__device__ __forceinline__ unsigned short f2bf(float f) {
  unsigned int u = __float_as_uint(f);
  unsigned int r = (u + 0x7FFFu + ((u >> 16) & 1u)) >> 16;
  return (unsigned short)r;
}
__device__ __forceinline__ float bf2f(unsigned short b) {
  return __uint_as_float(((unsigned int)b) << 16);
}

__device__ __forceinline__ void gload_lds16(const void* g, void* l) {
  __builtin_amdgcn_global_load_lds(
      (const __attribute__((address_space(1))) void*)g,
      (__attribute__((address_space(3))) void*)l, 16, 0, 0);
}

// ---------------- prep: compute_v + tiled W transposes + hist, one dispatch ----------------
// roles: [0,384) v1/v2 matvec; [384,432) W1 64x64 transpose tiles (12k x 4n);
//        [432,448) W2 tiles (4k x 4n); [448, 448+nbHist) histogram.

__device__ __forceinline__ void transpose_tile(const float* __restrict__ W,
                                               unsigned short* __restrict__ Wt,
                                               int K, int tk, int tn,
                                               float (*sT)[65], int t) {
  int lane = t & 63, rg = t >> 6;
  #pragma unroll
  for (int i = 0; i < 16; ++i) {
    int r = rg * 16 + i;  // k_local
    sT[lane][r] = W[(size_t)(tk * 64 + r) * HDIM + tn * 64 + lane];
  }
  __syncthreads();
  #pragma unroll
  for (int i = 0; i < 16; ++i) {
    int h = rg * 16 + i;  // h_local
    Wt[(size_t)(tn * 64 + h) * K + tk * 64 + lane] = f2bf(sT[h][lane]);
  }
}

__global__ __launch_bounds__(256) void k_prep(
    const float* __restrict__ We1, const float* __restrict__ ae1,
    const float* __restrict__ We2, const float* __restrict__ ae2,
    float* __restrict__ v1, float* __restrict__ v2,
    const float* __restrict__ W1, unsigned short* __restrict__ W1t,
    const float* __restrict__ W2, unsigned short* __restrict__ W2t,
    const int* __restrict__ dstArr, int* __restrict__ cnt, int E) {
  __shared__ float sT[64][65];
  int bid = blockIdx.x;
  int t = threadIdx.x;
  if (bid < 384) {
    int row = bid * 4 + (t >> 6);
    int lane = t & 63;
    const float* W = (row < FDIM) ? We1 : We2;
    const float* a = (row < FDIM) ? ae1 : ae2;
    int r = (row < FDIM) ? row : row - FDIM;
    float4 w = *(const float4*)&W[(size_t)r * HDIM + lane * 4];
    float4 av = *(const float4*)&a[lane * 4];
    float p = w.x * av.x + w.y * av.y + w.z * av.z + w.w * av.w;
    #pragma unroll
    for (int off = 32; off; off >>= 1) p += __shfl_down(p, off, 64);
    if (lane == 0) ((row < FDIM) ? v1 : v2)[r] = p;
  } else if (bid < 432) {
    int tile = bid - 384;  // 0..47 : W1 (K=768 -> 12 ktiles, 4 ntiles)
    transpose_tile(W1, W1t, FDIM, tile % 12, tile / 12, sT, t);
  } else if (bid < 448) {
    int tile = bid - 432;  // 0..15 : W2 (K=256 -> 4 ktiles, 4 ntiles)
    transpose_tile(W2, W2t, HDIM, tile & 3, tile >> 2, sT, t);
  } else {
    int e = (bid - 448) * 256 + t;
    if (e < E) atomicAdd(&cnt[dstArr[e]], 1);
  }
}

// ---------------- single-dispatch CSR scan (decoupled lookback) ----------------

__global__ __launch_bounds__(256) void k_scan_lb(const int* __restrict__ cnt,
                                                 int* __restrict__ offsets,
                                                 int* __restrict__ cursor,
                                                 int* __restrict__ bsums,
                                                 int* __restrict__ flags, int n) {
  __shared__ int s[256];
  __shared__ int r[256];
  const int b = blockIdx.x, t = threadIdx.x;
  int i = b * 256 + t;
  int v = (i < n) ? cnt[i] : 0;
  s[t] = v;
  __syncthreads();
  for (int off = 1; off < 256; off <<= 1) {
    int tv = (t >= off) ? s[t - off] : 0;
    __syncthreads();
    s[t] += tv;
    __syncthreads();
  }
  if (t == 255) {
    bsums[b] = s[255];
    __threadfence();
    __hip_atomic_store(&flags[b], 1, __ATOMIC_RELEASE, __HIP_MEMORY_SCOPE_AGENT);
  }
  int contrib = 0;
  if (t < b) {
    while (!__hip_atomic_load(&flags[t], __ATOMIC_ACQUIRE, __HIP_MEMORY_SCOPE_AGENT))
      __builtin_amdgcn_s_sleep(2);
    contrib = bsums[t];
  }
  r[t] = contrib;
  __syncthreads();
  #pragma unroll
  for (int off = 128; off; off >>= 1) {
    if (t < off) r[t] += r[t + off];
    __syncthreads();
  }
  int base = r[0];
  if (i < n) {
    int incl = base + s[t];
    offsets[i + 1] = incl;
    cursor[i] = incl - v;
    if (i == 0) offsets[0] = 0;
  }
}

// ---------------- GEMM body: C[M][HDIM] = A@Bt^T, fused row-dots ----------------

template <bool AF32, bool COUTBF>
__device__ __forceinline__ void gemm_body(unsigned char* lds,
                                          const void* __restrict__ Ain,
                                          const unsigned short* __restrict__ Bt,
                                          void* __restrict__ Cout,
                                          float* __restrict__ sOut,
                                          float* __restrict__ dOut,
                                          const float* __restrict__ a_src,
                                          const float* __restrict__ a_dst,
                                          int M, int K, int tile) {
  unsigned char* As = lds;
  unsigned char* Bs = lds + 8192;
  float* partS = (float*)(lds + 24576);         // [4][128]
  float* partD = (float*)(lds + 24576 + 2048);  // [4][128]
  const int t = threadIdx.x;
  const int l = t & 63;
  const int w = t >> 6;
  const int wm = w >> 2, wn = w & 3;
  const int bm = tile * BM;

  f32x4 acc[4][4] = {};

  int rowA = bm + (t & 127);
  if (rowA >= M) rowA = M - 1;
  const int cA = t >> 7;
  int rowAr = bm + (t >> 2);
  if (rowAr >= M) rowAr = M - 1;
  const int kbAr = t & 3;
  const int sAr = kbAr * 2048 + (t >> 2) * 16;
  const int nB = t & 255;
  const int cB0 = t >> 8;
  const int cB1 = 2 + (t >> 8);

  int aAddr[4], bAddr[4];
  #pragma unroll
  for (int mt = 0; mt < 4; ++mt) {
    int m = wm * 64 + mt * 16 + (l & 15);
    aAddr[mt] = (l >> 4) * 2048 + m * 16;
  }
  #pragma unroll
  for (int nt = 0; nt < 4; ++nt) {
    int nn = wn * 64 + nt * 16 + (l & 15);
    bAddr[nt] = (l >> 4) * 4096 + nn * 16;
  }

  const int nsteps = K / BK;
  for (int ks = 0; ks < nsteps; ++ks) {
    const int k0 = ks * BK;
    __syncthreads();
    if (AF32) {
      const float* A = (const float*)Ain;
      const float* p = A + (size_t)rowAr * K + k0 + kbAr * 8;
      float4 f0 = *(const float4*)p;
      float4 f1 = *(const float4*)(p + 4);
      short8 hv;
      hv[0] = (short)f2bf(f0.x); hv[1] = (short)f2bf(f0.y);
      hv[2] = (short)f2bf(f0.z); hv[3] = (short)f2bf(f0.w);
      hv[4] = (short)f2bf(f1.x); hv[5] = (short)f2bf(f1.y);
      hv[6] = (short)f2bf(f1.z); hv[7] = (short)f2bf(f1.w);
      *(short8*)(As + sAr) = hv;
    } else {
      const unsigned short* A = (const unsigned short*)Ain;
      gload_lds16(A + (size_t)rowA * K + k0 + cA * 8, As + t * 16);
    }
    gload_lds16(Bt + (size_t)nB * K + k0 + cB0 * 8, Bs + t * 16);
    gload_lds16(Bt + (size_t)nB * K + k0 + cB1 * 8, Bs + 8192 + t * 16);
    __syncthreads();

    short8 af[4], bfr[4];
    #pragma unroll
    for (int mt = 0; mt < 4; ++mt) af[mt] = *(const short8*)(As + aAddr[mt]);
    #pragma unroll
    for (int nt = 0; nt < 4; ++nt) bfr[nt] = *(const short8*)(Bs + bAddr[nt]);
    #pragma unroll
    for (int mt = 0; mt < 4; ++mt)
      #pragma unroll
      for (int nt = 0; nt < 4; ++nt)
        acc[mt][nt] = __builtin_amdgcn_mfma_f32_16x16x32_bf16(af[mt], bfr[nt], acc[mt][nt], 0, 0, 0);
  }

  float asv[4], adv[4];
  #pragma unroll
  for (int nt = 0; nt < 4; ++nt) {
    int col = wn * 64 + nt * 16 + (l & 15);
    asv[nt] = a_src[col];
    adv[nt] = a_dst[col];
  }
  #pragma unroll
  for (int mt = 0; mt < 4; ++mt) {
    int rloc = wm * 64 + mt * 16 + ((l >> 4) << 2);
    #pragma unroll
    for (int r = 0; r < 4; ++r) {
      int row = bm + rloc + r;
      float ps = 0.f, pd = 0.f;
      #pragma unroll
      for (int nt = 0; nt < 4; ++nt) {
        float v = acc[mt][nt][r];
        if (row < M) {
          int col = wn * 64 + nt * 16 + (l & 15);
          if (COUTBF)
            ((unsigned short*)Cout)[(size_t)row * HDIM + col] = f2bf(v);
          else
            ((float*)Cout)[(size_t)row * HDIM + col] = v;
        }
        ps += v * asv[nt];
        pd += v * adv[nt];
      }
      #pragma unroll
      for (int off = 1; off < 16; off <<= 1) {
        ps += __shfl_xor(ps, off, 64);
        pd += __shfl_xor(pd, off, 64);
      }
      if ((l & 15) == 0) {
        partS[wn * 128 + rloc + r] = ps;
        partD[wn * 128 + rloc + r] = pd;
      }
    }
  }
  __syncthreads();
  if (t < 128) {
    int row = bm + t;
    if (row < M) {
      sOut[row] = partS[t] + partS[128 + t] + partS[256 + t] + partS[384 + t];
      dOut[row] = partD[t] + partD[128 + t] + partD[256 + t] + partD[384 + t];
    }
  }
}

// ---------------- edge-alpha body (32 edges per 512-thread block, 4 per wave) ----------------

__device__ __forceinline__ void edge_body(unsigned char* lds,
                                          const float* __restrict__ ea,
                                          const float* __restrict__ v1,
                                          const float* __restrict__ v2,
                                          float* __restrict__ o1,
                                          float* __restrict__ o2, int E, int ebid) {
  float* sv1 = (float*)lds;
  float* sv2 = (float*)(lds + 3072);
  for (int i = threadIdx.x; i < FDIM; i += 512) { sv1[i] = v1[i]; sv2[i] = v2[i]; }
  __syncthreads();
  int lane = threadIdx.x & 63;
  int base = ebid * 32 + (threadIdx.x >> 6) * 4;
  #pragma unroll
  for (int q = 0; q < 4; ++q) {
    int e = base + q;
    if (e >= E) break;
    const float* row = ea + (size_t)e * FDIM;
    float p1 = 0.f, p2 = 0.f;
    #pragma unroll
    for (int t = 0; t < 3; ++t) {
      int idx = t * 256 + lane * 4;
      float4 x = *(const float4*)&row[idx];
      float4 a = *(const float4*)&sv1[idx];
      float4 b = *(const float4*)&sv2[idx];
      p1 += x.x * a.x + x.y * a.y + x.z * a.z + x.w * a.w;
      p2 += x.x * b.x + x.y * b.y + x.z * b.z + x.w * b.w;
    }
    #pragma unroll
    for (int off = 32; off; off >>= 1) {
      p1 += __shfl_down(p1, off, 64);
      p2 += __shfl_down(p2, off, 64);
    }
    if (lane == 0) { o1[e] = p1; o2[e] = p2; }
  }
}

// ---------------- fat kernel 1: GEMM1 || scatter || edge-alpha ----------------

#define NSCAT 98

__global__ __launch_bounds__(512) void k_fat1(
    const float* __restrict__ x, const unsigned short* __restrict__ W1t,
    unsigned short* __restrict__ xl1b, float* __restrict__ sArr, float* __restrict__ dArr,
    const float* __restrict__ as1, const float* __restrict__ ad1, int M,
    const float* __restrict__ ea, const float* __restrict__ v1,
    const float* __restrict__ v2, float* __restrict__ ae1Arr,
    float* __restrict__ ae2Arr, int E, int nGemm,
    const int* __restrict__ dstArr, int* __restrict__ cursor,
    int* __restrict__ elist) {
  __shared__ unsigned char lds[28672];
  int bid = blockIdx.x;
  if (bid < nGemm) {
    gemm_body<true, true>(lds, x, W1t, xl1b, sArr, dArr, as1, ad1, M, FDIM, bid);
  } else if (bid < nGemm + NSCAT) {
    int sb = bid - nGemm;
    for (int e = sb * 512 + threadIdx.x; e < E; e += NSCAT * 512) {
      int p = atomicAdd(&cursor[dstArr[e]], 1);
      elist[p] = e;
    }
  } else {
    edge_body(lds, ea, v1, v2, ae1Arr, ae2Arr, E, bid - nGemm - NSCAT);
  }
}

__global__ __launch_bounds__(512) void k_gemm2(
    const unsigned short* __restrict__ hb, const unsigned short* __restrict__ W2t,
    unsigned short* __restrict__ xl2b, float* __restrict__ sArr, float* __restrict__ dArr,
    const float* __restrict__ as2, const float* __restrict__ ad2, int M) {
  __shared__ unsigned char lds[28672];
  gemm_body<false, true>(lds, hb, W2t, xl2b, sArr, dArr, as2, ad2, M, HDIM, blockIdx.x);
}

// ---------------- shared per-node aggregation body (one wave, online softmax) ----------------

__device__ __forceinline__ void agg_node(const unsigned short* __restrict__ xlb,
                                         const float* __restrict__ sArr,
                                         float dnode,
                                         const float* __restrict__ aeArr,
                                         const int* __restrict__ src,
                                         const int* __restrict__ elist,
                                         int beg, int end, int lane,
                                         float& a0, float& a1, float& a2, float& a3) {
  float run_m = -1e30f, run_den = 0.f;
  a0 = a1 = a2 = a3 = 0.f;
  for (int c0 = beg; c0 < end; c0 += 64) {
    int j = c0 + lane;
    float al = -1e30f;
    int sj = 0;
    if (j < end) {
      int e = elist[j];
      sj = src[e];
      float a = sArr[sj] + dnode + aeArr[e];
      al = (a > 0.f) ? a : 0.2f * a;
    }
    float cm = al;
    #pragma unroll
    for (int off = 32; off; off >>= 1) cm = fmaxf(cm, __shfl_xor(cm, off, 64));
    float new_m = fmaxf(run_m, cm);
    float ev = (j < end) ? expf(al - new_m) : 0.f;
    float csum = ev;
    #pragma unroll
    for (int off = 32; off; off >>= 1) csum += __shfl_xor(csum, off, 64);
    float scale = expf(run_m - new_m);
    run_den = run_den * scale + csum;
    a0 *= scale; a1 *= scale; a2 *= scale; a3 *= scale;
    int cdeg = end - c0;
    if (cdeg > 64) cdeg = 64;
    for (int q = 0; q < cdeg; ++q) {
      float wgt = __shfl(ev, q, 64);
      int sq = __shfl(sj, q, 64);
      us4 v = *(const us4*)(xlb + (size_t)sq * HDIM + lane * 4);
      a0 += wgt * bf2f(v[0]); a1 += wgt * bf2f(v[1]);
      a2 += wgt * bf2f(v[2]); a3 += wgt * bf2f(v[3]);
    }
    run_m = new_m;
  }
  float inv = (end > beg) ? 1.f / run_den : 0.f;
  a0 *= inv; a1 *= inv; a2 *= inv; a3 *= inv;
}

// ---------------- layer-1 aggregate (all nodes, relu, bf16 out) ----------------

__global__ __launch_bounds__(256) void k_aggregate1(const unsigned short* __restrict__ xlb,
                                                    const float* __restrict__ sArr,
                                                    const float* __restrict__ dArr,
                                                    const float* __restrict__ aeArr,
                                                    const int* __restrict__ src,
                                                    const int* __restrict__ offsets,
                                                    const int* __restrict__ elist,
                                                    const float* __restrict__ bias,
                                                    unsigned short* __restrict__ outb,
                                                    int n) {
  int node = blockIdx.x * 4 + (threadIdx.x >> 6);
  if (node >= n) return;
  int lane = threadIdx.x & 63;
  int beg = offsets[node], end = offsets[node + 1];
  float a0, a1, a2, a3;
  agg_node(xlb, sArr, dArr[node], aeArr, src, elist, beg, end, lane, a0, a1, a2, a3);
  float4 bv = *(const float4*)(bias + lane * 4);
  float o0 = fmaxf(a0 + bv.x, 0.f), o1 = fmaxf(a1 + bv.y, 0.f);
  float o2 = fmaxf(a2 + bv.z, 0.f), o3 = fmaxf(a3 + bv.w, 0.f);
  us4 ov;
  ov[0] = f2bf(o0); ov[1] = f2bf(o1); ov[2] = f2bf(o2); ov[3] = f2bf(o3);
  *(us4*)(outb + (size_t)node * HDIM + lane * 4) = ov;
}

// ---------------- fused layer-2 aggregate (pair nodes only) + head ----------------

__global__ __launch_bounds__(256) void k_agg2head(const unsigned short* __restrict__ xl2b,
                                                  const float* __restrict__ sArr,
                                                  const float* __restrict__ dArr,
                                                  const float* __restrict__ aeArr,
                                                  const int* __restrict__ src,
                                                  const int* __restrict__ offsets,
                                                  const int* __restrict__ elist,
                                                  const float* __restrict__ b2,
                                                  const int* __restrict__ nodes,
                                                  const float* __restrict__ Wp,
                                                  const float* __restrict__ bp,
                                                  float* __restrict__ out, int Bn) {
  __shared__ float tls[2][2][HDIM];
  int wv = threadIdx.x >> 6;
  int lane = threadIdx.x & 63;
  int pl = wv >> 1;
  int side = wv & 1;
  int b = blockIdx.x * 2 + pl;
  if (b < Bn) {
    int node = nodes[side * Bn + b];
    int beg = offsets[node], end = offsets[node + 1];
    float a0, a1, a2, a3;
    agg_node(xl2b, sArr, dArr[node], aeArr, src, elist, beg, end, lane, a0, a1, a2, a3);
    float4 bv = *(const float4*)(b2 + lane * 4);
    float* dstp = &tls[pl][side][lane * 4];
    dstp[0] = a0 + bv.x; dstp[1] = a1 + bv.y;
    dstp[2] = a2 + bv.z; dstp[3] = a3 + bv.w;
  }
  __syncthreads();
  if (b < Bn && side == 0) {
    float4 t0 = *(const float4*)&tls[pl][0][lane * 4];
    float4 t1 = *(const float4*)&tls[pl][1][lane * 4];
    float c0 = t0.x * t1.x, c1 = t0.y * t1.y, c2 = t0.z * t1.z, c3 = t0.w * t1.w;
    int h0 = lane * 4;
    float s0 = c0 * Wp[h0 * 3 + 0] + c1 * Wp[(h0 + 1) * 3 + 0] +
               c2 * Wp[(h0 + 2) * 3 + 0] + c3 * Wp[(h0 + 3) * 3 + 0];
    float s1 = c0 * Wp[h0 * 3 + 1] + c1 * Wp[(h0 + 1) * 3 + 1] +
               c2 * Wp[(h0 + 2) * 3 + 1] + c3 * Wp[(h0 + 3) * 3 + 1];
    float s2 = c0 * Wp[h0 * 3 + 2] + c1 * Wp[(h0 + 1) * 3 + 2] +
               c2 * Wp[(h0 + 2) * 3 + 2] + c3 * Wp[(h0 + 3) * 3 + 2];
    #pragma unroll
    for (int off = 32; off; off >>= 1) {
      s0 += __shfl_down(s0, off, 64);
      s1 += __shfl_down(s1, off, 64);
      s2 += __shfl_down(s2, off, 64);
    }
    if (lane == 0) {
      out[b * 3 + 0] = s0 + bp[0];
      out[b * 3 + 1] = s1 + bp[1];
      out[b * 3 + 2] = s2 + bp[2];
    }
  }
}

// ---------------- launch ----------------

extern "C" void kernel_launch(void* const* d_in, const int* in_sizes, int n_in,
                              void* d_out, int out_size, void* d_ws, size_t ws_size,
                              hipStream_t stream) {
  const float* x         = (const float*)d_in[0];
  const float* edge_attr = (const float*)d_in[1];
  const float* W1  = (const float*)d_in[2];
  const float* as1 = (const float*)d_in[3];
  const float* ad1 = (const float*)d_in[4];
  const float* We1 = (const float*)d_in[5];
  const float* ae1 = (const float*)d_in[6];
  const float* b1  = (const float*)d_in[7];
  const float* W2  = (const float*)d_in[8];
  const float* as2 = (const float*)d_in[9];
  const float* ad2 = (const float*)d_in[10];
  const float* We2 = (const float*)d_in[11];
  const float* ae2 = (const float*)d_in[12];
  const float* b2  = (const float*)d_in[13];
  const float* Wp  = (const float*)d_in[14];
  const float* bp  = (const float*)d_in[15];
  const int* edge_index = (const int*)d_in[16];
  const int* nodes      = (const int*)d_in[17];

  const int N  = in_sizes[0] / FDIM;
  const int E  = in_sizes[16] / 2;
  const int Bn = in_sizes[17] / 2;
  const int* srcArr = edge_index;
  const int* dstArr = edge_index + E;

  char* w = (char*)d_ws;
  auto carve = [&](size_t bytes) -> void* {
    void* p = (void*)w;
    w += (bytes + 255) & ~(size_t)255;
    return p;
  };
  unsigned short* xl1b   = (unsigned short*)carve(2 * (size_t)N * HDIM);  // also xl2b
  unsigned short* hb     = (unsigned short*)carve(2 * (size_t)N * HDIM);
  unsigned short* W1t    = (unsigned short*)carve(2 * (size_t)FDIM * HDIM);
  unsigned short* W2t    = (unsigned short*)carve(2 * (size_t)HDIM * HDIM);
  float* ae1Arr = (float*)carve(sizeof(float) * E);
  float* ae2Arr = (float*)carve(sizeof(float) * E);
  float* sArr = (float*)carve(sizeof(float) * N);
  float* dArr = (float*)carve(sizeof(float) * N);
  float* v1 = (float*)carve(sizeof(float) * FDIM);
  float* v2 = (float*)carve(sizeof(float) * FDIM);
  int* cntflags = (int*)carve(sizeof(int) * (N + 256));  // cnt[N] + flags[256]
  int* offsets = (int*)carve(sizeof(int) * (N + 1));
  int* cursor  = (int*)carve(sizeof(int) * N);
  int* elist   = (int*)carve(sizeof(int) * E);
  int* bsums   = (int*)carve(sizeof(int) * 256);

  int* cnt = cntflags;
  int* flags = cntflags + N;

  const int nbScan = (N + 255) / 256;
  const int nbHist = (E + 255) / 256;
  const int nGemm = (N + BM - 1) / BM;
  const int nEdge = (E + 31) / 32;

  // zero cnt + lookback flags (one memset)
  hipMemsetAsync(cntflags, 0, sizeof(int) * (N + 256), stream);
  // prep: compute_v + tiled weight transpose + hist
  k_prep<<<448 + nbHist, 256, 0, stream>>>(We1, ae1, We2, ae2, v1, v2,
                                           W1, W1t, W2, W2t, dstArr, cnt, E);
  // single-dispatch scan (offsets + cursor)
  k_scan_lb<<<nbScan, 256, 0, stream>>>(cnt, offsets, cursor, bsums, flags, N);

  // fat: GEMM1 (+row-dots, bf16 C) || scatter || edge-alpha (both layers)
  k_fat1<<<nGemm + NSCAT + nEdge, 512, 0, stream>>>(
      x, W1t, xl1b, sArr, dArr, as1, ad1, N,
      edge_attr, v1, v2, ae1Arr, ae2Arr, E, nGemm, dstArr, cursor, elist);
  // layer 1 aggregate (bf16 gather) -> hb (bf16)
  k_aggregate1<<<(N + 3) / 4, 256, 0, stream>>>(xl1b, sArr, dArr, ae1Arr, srcArr,
                                                offsets, elist, b1, hb, N);
  // layer 2 GEMM (xl2 bf16, aliases xl1b buffer)
  k_gemm2<<<nGemm, 512, 0, stream>>>(hb, W2t, xl1b, sArr, dArr, as2, ad2, N);
  // fused layer-2 aggregate (pair nodes only) + head
  k_agg2head<<<(Bn + 1) / 2, 256, 0, stream>>>(xl1b, sArr, dArr, ae2Arr, srcArr,
                                               offsets, elist, b2, nodes, Wp, bp,
                                               (float*)d_out, Bn);
}

// Round 10
// 266.012 us; speedup vs baseline: 1.1059x; 1.0374x over previous
//
#include <hip/hip_runtime.h>
#include <math.h>

#define HDIM 256
#define FDIM 768
#define BM 128
#define BK 32

typedef __attribute__((ext_vector_type(8))) short short8;
typedef __attribute__((ext_vector_type(4))) float f32x4;
typedef __attribute__((ext_vector_type(4))) unsigned short us4;

__device__ __forceinline__ unsigned short f2bf(float f) {
  unsigned int u = __float_as_uint(f);
  unsigned int r = (u + 0x7FFFu + ((u >> 16) & 1u)) >> 16;
  return (unsigned short)r;
}
__device__ __forceinline__ float bf2f(unsigned short b) {
  return __uint_as_float(((unsigned int)b) << 16);
}

__device__ __forceinline__ void gload_lds16(const void* g, void* l) {
  __builtin_amdgcn_global_load_lds(
      (const __attribute__((address_space(1))) void*)g,
      (__attribute__((address_space(3))) void*)l, 16, 0, 0);
}

// ---------------- prep: compute_v + tiled W transposes + hist, one dispatch ----------------

__device__ __forceinline__ void transpose_tile(const float* __restrict__ W,
                                               unsigned short* __restrict__ Wt,
                                               int K, int tk, int tn,
                                               float (*sT)[65], int t) {
  int lane = t & 63, rg = t >> 6;
  #pragma unroll
  for (int i = 0; i < 16; ++i) {
    int r = rg * 16 + i;  // k_local
    sT[lane][r] = W[(size_t)(tk * 64 + r) * HDIM + tn * 64 + lane];
  }
  __syncthreads();
  #pragma unroll
  for (int i = 0; i < 16; ++i) {
    int h = rg * 16 + i;  // h_local
    Wt[(size_t)(tn * 64 + h) * K + tk * 64 + lane] = f2bf(sT[h][lane]);
  }
}

__global__ __launch_bounds__(256) void k_prep(
    const float* __restrict__ We1, const float* __restrict__ ae1,
    const float* __restrict__ We2, const float* __restrict__ ae2,
    float* __restrict__ v1, float* __restrict__ v2,
    const float* __restrict__ W1, unsigned short* __restrict__ W1t,
    const float* __restrict__ W2, unsigned short* __restrict__ W2t,
    const int* __restrict__ dstArr, int* __restrict__ cnt, int E) {
  __shared__ float sT[64][65];
  int bid = blockIdx.x;
  int t = threadIdx.x;
  if (bid < 384) {
    int row = bid * 4 + (t >> 6);
    int lane = t & 63;
    const float* W = (row < FDIM) ? We1 : We2;
    const float* a = (row < FDIM) ? ae1 : ae2;
    int r = (row < FDIM) ? row : row - FDIM;
    float4 w = *(const float4*)&W[(size_t)r * HDIM + lane * 4];
    float4 av = *(const float4*)&a[lane * 4];
    float p = w.x * av.x + w.y * av.y + w.z * av.z + w.w * av.w;
    #pragma unroll
    for (int off = 32; off; off >>= 1) p += __shfl_down(p, off, 64);
    if (lane == 0) ((row < FDIM) ? v1 : v2)[r] = p;
  } else if (bid < 432) {
    int tile = bid - 384;  // W1: 12 ktiles x 4 ntiles
    transpose_tile(W1, W1t, FDIM, tile % 12, tile / 12, sT, t);
  } else if (bid < 448) {
    int tile = bid - 432;  // W2: 4 ktiles x 4 ntiles
    transpose_tile(W2, W2t, HDIM, tile & 3, tile >> 2, sT, t);
  } else {
    int e = (bid - 448) * 256 + t;
    if (e < E) atomicAdd(&cnt[dstArr[e]], 1);
  }
}

// ---------------- single-dispatch CSR scan (decoupled lookback) ----------------

__global__ __launch_bounds__(256) void k_scan_lb(const int* __restrict__ cnt,
                                                 int* __restrict__ offsets,
                                                 int* __restrict__ cursor,
                                                 int* __restrict__ bsums,
                                                 int* __restrict__ flags, int n) {
  __shared__ int s[256];
  __shared__ int r[256];
  const int b = blockIdx.x, t = threadIdx.x;
  int i = b * 256 + t;
  int v = (i < n) ? cnt[i] : 0;
  s[t] = v;
  __syncthreads();
  for (int off = 1; off < 256; off <<= 1) {
    int tv = (t >= off) ? s[t - off] : 0;
    __syncthreads();
    s[t] += tv;
    __syncthreads();
  }
  if (t == 255) {
    bsums[b] = s[255];
    __threadfence();
    __hip_atomic_store(&flags[b], 1, __ATOMIC_RELEASE, __HIP_MEMORY_SCOPE_AGENT);
  }
  int contrib = 0;
  if (t < b) {
    while (!__hip_atomic_load(&flags[t], __ATOMIC_ACQUIRE, __HIP_MEMORY_SCOPE_AGENT))
      __builtin_amdgcn_s_sleep(2);
    contrib = bsums[t];
  }
  r[t] = contrib;
  __syncthreads();
  #pragma unroll
  for (int off = 128; off; off >>= 1) {
    if (t < off) r[t] += r[t + off];
    __syncthreads();
  }
  int base = r[0];
  if (i < n) {
    int incl = base + s[t];
    offsets[i + 1] = incl;
    cursor[i] = incl - v;
    if (i == 0) offsets[0] = 0;
  }
}

// ---------------- GEMM body: C[M][HDIM] = A@Bt^T, fused row-dots ----------------

template <bool AF32, bool COUTBF>
__device__ __forceinline__ void gemm_body(unsigned char* lds,
                                          const void* __restrict__ Ain,
                                          const unsigned short* __restrict__ Bt,
                                          void* __restrict__ Cout,
                                          float* __restrict__ sOut,
                                          float* __restrict__ dOut,
                                          const float* __restrict__ a_src,
                                          const float* __restrict__ a_dst,
                                          int M, int K, int tile) {
  unsigned char* As = lds;
  unsigned char* Bs = lds + 8192;
  float* partS = (float*)(lds + 24576);         // [4][128]
  float* partD = (float*)(lds + 24576 + 2048);  // [4][128]
  const int t = threadIdx.x;
  const int l = t & 63;
  const int w = t >> 6;
  const int wm = w >> 2, wn = w & 3;
  const int bm = tile * BM;

  f32x4 acc[4][4] = {};

  int rowA = bm + (t & 127);
  if (rowA >= M) rowA = M - 1;
  const int cA = t >> 7;
  int rowAr = bm + (t >> 2);
  if (rowAr >= M) rowAr = M - 1;
  const int kbAr = t & 3;
  const int sAr = kbAr * 2048 + (t >> 2) * 16;
  const int nB = t & 255;
  const int cB0 = t >> 8;
  const int cB1 = 2 + (t >> 8);

  int aAddr[4], bAddr[4];
  #pragma unroll
  for (int mt = 0; mt < 4; ++mt) {
    int m = wm * 64 + mt * 16 + (l & 15);
    aAddr[mt] = (l >> 4) * 2048 + m * 16;
  }
  #pragma unroll
  for (int nt = 0; nt < 4; ++nt) {
    int nn = wn * 64 + nt * 16 + (l & 15);
    bAddr[nt] = (l >> 4) * 4096 + nn * 16;
  }

  const int nsteps = K / BK;
  for (int ks = 0; ks < nsteps; ++ks) {
    const int k0 = ks * BK;
    __syncthreads();
    if (AF32) {
      const float* A = (const float*)Ain;
      const float* p = A + (size_t)rowAr * K + k0 + kbAr * 8;
      float4 f0 = *(const float4*)p;
      float4 f1 = *(const float4*)(p + 4);
      short8 hv;
      hv[0] = (short)f2bf(f0.x); hv[1] = (short)f2bf(f0.y);
      hv[2] = (short)f2bf(f0.z); hv[3] = (short)f2bf(f0.w);
      hv[4] = (short)f2bf(f1.x); hv[5] = (short)f2bf(f1.y);
      hv[6] = (short)f2bf(f1.z); hv[7] = (short)f2bf(f1.w);
      *(short8*)(As + sAr) = hv;
    } else {
      const unsigned short* A = (const unsigned short*)Ain;
      gload_lds16(A + (size_t)rowA * K + k0 + cA * 8, As + t * 16);
    }
    gload_lds16(Bt + (size_t)nB * K + k0 + cB0 * 8, Bs + t * 16);
    gload_lds16(Bt + (size_t)nB * K + k0 + cB1 * 8, Bs + 8192 + t * 16);
    __syncthreads();

    short8 af[4], bfr[4];
    #pragma unroll
    for (int mt = 0; mt < 4; ++mt) af[mt] = *(const short8*)(As + aAddr[mt]);
    #pragma unroll
    for (int nt = 0; nt < 4; ++nt) bfr[nt] = *(const short8*)(Bs + bAddr[nt]);
    #pragma unroll
    for (int mt = 0; mt < 4; ++mt)
      #pragma unroll
      for (int nt = 0; nt < 4; ++nt)
        acc[mt][nt] = __builtin_amdgcn_mfma_f32_16x16x32_bf16(af[mt], bfr[nt], acc[mt][nt], 0, 0, 0);
  }

  float asv[4], adv[4];
  #pragma unroll
  for (int nt = 0; nt < 4; ++nt) {
    int col = wn * 64 + nt * 16 + (l & 15);
    asv[nt] = a_src[col];
    adv[nt] = a_dst[col];
  }
  #pragma unroll
  for (int mt = 0; mt < 4; ++mt) {
    int rloc = wm * 64 + mt * 16 + ((l >> 4) << 2);
    #pragma unroll
    for (int r = 0; r < 4; ++r) {
      int row = bm + rloc + r;
      float ps = 0.f, pd = 0.f;
      #pragma unroll
      for (int nt = 0; nt < 4; ++nt) {
        float v = acc[mt][nt][r];
        if (row < M) {
          int col = wn * 64 + nt * 16 + (l & 15);
          if (COUTBF)
            ((unsigned short*)Cout)[(size_t)row * HDIM + col] = f2bf(v);
          else
            ((float*)Cout)[(size_t)row * HDIM + col] = v;
        }
        ps += v * asv[nt];
        pd += v * adv[nt];
      }
      #pragma unroll
      for (int off = 1; off < 16; off <<= 1) {
        ps += __shfl_xor(ps, off, 64);
        pd += __shfl_xor(pd, off, 64);
      }
      if ((l & 15) == 0) {
        partS[wn * 128 + rloc + r] = ps;
        partD[wn * 128 + rloc + r] = pd;
      }
    }
  }
  __syncthreads();
  if (t < 128) {
    int row = bm + t;
    if (row < M) {
      sOut[row] = partS[t] + partS[128 + t] + partS[256 + t] + partS[384 + t];
      dOut[row] = partD[t] + partD[128 + t] + partD[256 + t] + partD[384 + t];
    }
  }
}

// ---------------- edge-alpha body (32 edges per 512-thread block, 4 per wave) ----------------

__device__ __forceinline__ void edge_body(unsigned char* lds,
                                          const float* __restrict__ ea,
                                          const float* __restrict__ v1,
                                          const float* __restrict__ v2,
                                          float* __restrict__ o1,
                                          float* __restrict__ o2, int E, int ebid) {
  float* sv1 = (float*)lds;
  float* sv2 = (float*)(lds + 3072);
  for (int i = threadIdx.x; i < FDIM; i += 512) { sv1[i] = v1[i]; sv2[i] = v2[i]; }
  __syncthreads();
  int lane = threadIdx.x & 63;
  int base = ebid * 32 + (threadIdx.x >> 6) * 4;
  #pragma unroll
  for (int q = 0; q < 4; ++q) {
    int e = base + q;
    if (e >= E) break;
    const float* row = ea + (size_t)e * FDIM;
    float p1 = 0.f, p2 = 0.f;
    #pragma unroll
    for (int t = 0; t < 3; ++t) {
      int idx = t * 256 + lane * 4;
      float4 x = *(const float4*)&row[idx];
      float4 a = *(const float4*)&sv1[idx];
      float4 b = *(const float4*)&sv2[idx];
      p1 += x.x * a.x + x.y * a.y + x.z * a.z + x.w * a.w;
      p2 += x.x * b.x + x.y * b.y + x.z * b.z + x.w * b.w;
    }
    #pragma unroll
    for (int off = 32; off; off >>= 1) {
      p1 += __shfl_down(p1, off, 64);
      p2 += __shfl_down(p2, off, 64);
    }
    if (lane == 0) { o1[e] = p1; o2[e] = p2; }
  }
}

// ---------------- fat kernel 1: GEMM1 || scatter || edge-alpha ----------------

#define NSCAT 98

__global__ __launch_bounds__(512) void k_fat1(
    const float* __restrict__ x, const unsigned short* __restrict__ W1t,
    unsigned short* __restrict__ xl1b, float* __restrict__ sArr, float* __restrict__ dArr,
    const float* __restrict__ as1, const float* __restrict__ ad1, int M,
    const float* __restrict__ ea, const float* __restrict__ v1,
    const float* __restrict__ v2, float* __restrict__ ae1Arr,
    float* __restrict__ ae2Arr, int E, int nGemm,
    const int* __restrict__ dstArr, int* __restrict__ cursor,
    int* __restrict__ elist) {
  __shared__ unsigned char lds[28672];
  int bid = blockIdx.x;
  if (bid < nGemm) {
    gemm_body<true, true>(lds, x, W1t, xl1b, sArr, dArr, as1, ad1, M, FDIM, bid);
  } else if (bid < nGemm + NSCAT) {
    int sb = bid - nGemm;
    for (int e = sb * 512 + threadIdx.x; e < E; e += NSCAT * 512) {
      int p = atomicAdd(&cursor[dstArr[e]], 1);
      elist[p] = e;
    }
  } else {
    edge_body(lds, ea, v1, v2, ae1Arr, ae2Arr, E, bid - nGemm - NSCAT);
  }
}

__global__ __launch_bounds__(512) void k_gemm2(
    const unsigned short* __restrict__ hb, const unsigned short* __restrict__ W2t,
    unsigned short* __restrict__ xl2b, float* __restrict__ sArr, float* __restrict__ dArr,
    const float* __restrict__ as2, const float* __restrict__ ad2, int M) {
  __shared__ unsigned char lds[28672];
  gemm_body<false, true>(lds, hb, W2t, xl2b, sArr, dArr, as2, ad2, M, HDIM, blockIdx.x);
}

// ---------------- 16-lane-group aggregation body (online softmax, chunk=16) ----------------
// gl = lane index within 16-lane group; a[16] covers cols {s*64 + gl*4 + j}.

__device__ __forceinline__ void agg_node16(const unsigned short* __restrict__ xlb,
                                           const float* __restrict__ sArr,
                                           float dnode,
                                           const float* __restrict__ aeArr,
                                           const int* __restrict__ src,
                                           const int* __restrict__ elist,
                                           int beg, int end, int gl, float* a) {
  float run_m = -1e30f, run_den = 0.f;
  #pragma unroll
  for (int i = 0; i < 16; ++i) a[i] = 0.f;
  for (int c0 = beg; c0 < end; c0 += 16) {
    int j = c0 + gl;
    float al = -1e30f;
    int sj = 0;
    if (j < end) {
      int e = elist[j];
      sj = src[e];
      float aa = sArr[sj] + dnode + aeArr[e];
      al = (aa > 0.f) ? aa : 0.2f * aa;
    }
    float cm = al;
    #pragma unroll
    for (int off = 8; off; off >>= 1) cm = fmaxf(cm, __shfl_xor(cm, off, 16));
    float new_m = fmaxf(run_m, cm);
    float ev = (j < end) ? expf(al - new_m) : 0.f;
    float cs = ev;
    #pragma unroll
    for (int off = 8; off; off >>= 1) cs += __shfl_xor(cs, off, 16);
    float scale = expf(run_m - new_m);
    run_den = run_den * scale + cs;
    #pragma unroll
    for (int i = 0; i < 16; ++i) a[i] *= scale;
    int cdeg = end - c0;
    if (cdeg > 16) cdeg = 16;
    for (int q = 0; q < cdeg; ++q) {
      float wgt = __shfl(ev, q, 16);
      int sq = __shfl(sj, q, 16);
      const unsigned short* rp = xlb + (size_t)sq * HDIM + gl * 4;
      #pragma unroll
      for (int s = 0; s < 4; ++s) {
        us4 v = *(const us4*)(rp + s * 64);
        a[s * 4 + 0] += wgt * bf2f(v[0]);
        a[s * 4 + 1] += wgt * bf2f(v[1]);
        a[s * 4 + 2] += wgt * bf2f(v[2]);
        a[s * 4 + 3] += wgt * bf2f(v[3]);
      }
    }
    run_m = new_m;
  }
  float inv = (end > beg) ? 1.f / run_den : 0.f;
  #pragma unroll
  for (int i = 0; i < 16; ++i) a[i] *= inv;
}

// ---------------- layer-1 aggregate: 16 nodes per 256-thread block ----------------

__global__ __launch_bounds__(256) void k_aggregate1(const unsigned short* __restrict__ xlb,
                                                    const float* __restrict__ sArr,
                                                    const float* __restrict__ dArr,
                                                    const float* __restrict__ aeArr,
                                                    const int* __restrict__ src,
                                                    const int* __restrict__ offsets,
                                                    const int* __restrict__ elist,
                                                    const float* __restrict__ bias,
                                                    unsigned short* __restrict__ outb,
                                                    int n) {
  int grp = threadIdx.x >> 4;
  int gl = threadIdx.x & 15;
  int node = blockIdx.x * 16 + grp;
  if (node >= n) return;
  int beg = offsets[node], end = offsets[node + 1];
  float a[16];
  agg_node16(xlb, sArr, dArr[node], aeArr, src, elist, beg, end, gl, a);
  unsigned short* orow = outb + (size_t)node * HDIM + gl * 4;
  #pragma unroll
  for (int s = 0; s < 4; ++s) {
    float4 bv = *(const float4*)(bias + s * 64 + gl * 4);
    us4 ov;
    ov[0] = f2bf(fmaxf(a[s * 4 + 0] + bv.x, 0.f));
    ov[1] = f2bf(fmaxf(a[s * 4 + 1] + bv.y, 0.f));
    ov[2] = f2bf(fmaxf(a[s * 4 + 2] + bv.z, 0.f));
    ov[3] = f2bf(fmaxf(a[s * 4 + 3] + bv.w, 0.f));
    *(us4*)(orow + s * 64) = ov;
  }
}

// ---------------- fused layer-2 aggregate (pair nodes only) + head: 8 pairs/block ----------------

__global__ __launch_bounds__(256) void k_agg2head(const unsigned short* __restrict__ xl2b,
                                                  const float* __restrict__ sArr,
                                                  const float* __restrict__ dArr,
                                                  const float* __restrict__ aeArr,
                                                  const int* __restrict__ src,
                                                  const int* __restrict__ offsets,
                                                  const int* __restrict__ elist,
                                                  const float* __restrict__ b2,
                                                  const int* __restrict__ nodes,
                                                  const float* __restrict__ Wp,
                                                  const float* __restrict__ bp,
                                                  float* __restrict__ out, int Bn) {
  __shared__ float tls[8][2][HDIM];
  int grp = threadIdx.x >> 4;   // 0..15
  int gl = threadIdx.x & 15;
  int pl = grp >> 1;            // pair 0..7
  int side = grp & 1;
  int b = blockIdx.x * 8 + pl;
  if (b < Bn) {
    int node = nodes[side * Bn + b];
    int beg = offsets[node], end = offsets[node + 1];
    float a[16];
    agg_node16(xl2b, sArr, dArr[node], aeArr, src, elist, beg, end, gl, a);
    #pragma unroll
    for (int s = 0; s < 4; ++s) {
      int h = s * 64 + gl * 4;
      float4 bv = *(const float4*)(b2 + h);
      float* dstp = &tls[pl][side][h];
      dstp[0] = a[s * 4 + 0] + bv.x;
      dstp[1] = a[s * 4 + 1] + bv.y;
      dstp[2] = a[s * 4 + 2] + bv.z;
      dstp[3] = a[s * 4 + 3] + bv.w;
    }
  }
  __syncthreads();
  if (b < Bn && side == 0) {
    float s0 = 0.f, s1 = 0.f, s2 = 0.f;
    #pragma unroll
    for (int s = 0; s < 4; ++s) {
      int h = s * 64 + gl * 4;
      float4 t0 = *(const float4*)&tls[pl][0][h];
      float4 t1 = *(const float4*)&tls[pl][1][h];
      float c0 = t0.x * t1.x, c1 = t0.y * t1.y, c2 = t0.z * t1.z, c3 = t0.w * t1.w;
      s0 += c0 * Wp[h * 3 + 0] + c1 * Wp[(h + 1) * 3 + 0] +
            c2 * Wp[(h + 2) * 3 + 0] + c3 * Wp[(h + 3) * 3 + 0];
      s1 += c0 * Wp[h * 3 + 1] + c1 * Wp[(h + 1) * 3 + 1] +
            c2 * Wp[(h + 2) * 3 + 1] + c3 * Wp[(h + 3) * 3 + 1];
      s2 += c0 * Wp[h * 3 + 2] + c1 * Wp[(h + 1) * 3 + 2] +
            c2 * Wp[(h + 2) * 3 + 2] + c3 * Wp[(h + 3) * 3 + 2];
    }
    #pragma unroll
    for (int off = 8; off; off >>= 1) {
      s0 += __shfl_down(s0, off, 16);
      s1 += __shfl_down(s1, off, 16);
      s2 += __shfl_down(s2, off, 16);
    }
    if (gl == 0) {
      out[b * 3 + 0] = s0 + bp[0];
      out[b * 3 + 1] = s1 + bp[1];
      out[b * 3 + 2] = s2 + bp[2];
    }
  }
}

// ---------------- launch ----------------

extern "C" void kernel_launch(void* const* d_in, const int* in_sizes, int n_in,
                              void* d_out, int out_size, void* d_ws, size_t ws_size,
                              hipStream_t stream) {
  const float* x         = (const float*)d_in[0];
  const float* edge_attr = (const float*)d_in[1];
  const float* W1  = (const float*)d_in[2];
  const float* as1 = (const float*)d_in[3];
  const float* ad1 = (const float*)d_in[4];
  const float* We1 = (const float*)d_in[5];
  const float* ae1 = (const float*)d_in[6];
  const float* b1  = (const float*)d_in[7];
  const float* W2  = (const float*)d_in[8];
  const float* as2 = (const float*)d_in[9];
  const float* ad2 = (const float*)d_in[10];
  const float* We2 = (const float*)d_in[11];
  const float* ae2 = (const float*)d_in[12];
  const float* b2  = (const float*)d_in[13];
  const float* Wp  = (const float*)d_in[14];
  const float* bp  = (const float*)d_in[15];
  const int* edge_index = (const int*)d_in[16];
  const int* nodes      = (const int*)d_in[17];

  const int N  = in_sizes[0] / FDIM;
  const int E  = in_sizes[16] / 2;
  const int Bn = in_sizes[17] / 2;
  const int* srcArr = edge_index;
  const int* dstArr = edge_index + E;

  char* w = (char*)d_ws;
  auto carve = [&](size_t bytes) -> void* {
    void* p = (void*)w;
    w += (bytes + 255) & ~(size_t)255;
    return p;
  };
  unsigned short* xl1b   = (unsigned short*)carve(2 * (size_t)N * HDIM);  // also xl2b
  unsigned short* hb     = (unsigned short*)carve(2 * (size_t)N * HDIM);
  unsigned short* W1t    = (unsigned short*)carve(2 * (size_t)FDIM * HDIM);
  unsigned short* W2t    = (unsigned short*)carve(2 * (size_t)HDIM * HDIM);
  float* ae1Arr = (float*)carve(sizeof(float) * E);
  float* ae2Arr = (float*)carve(sizeof(float) * E);
  float* sArr = (float*)carve(sizeof(float) * N);
  float* dArr = (float*)carve(sizeof(float) * N);
  float* v1 = (float*)carve(sizeof(float) * FDIM);
  float* v2 = (float*)carve(sizeof(float) * FDIM);
  int* cntflags = (int*)carve(sizeof(int) * (N + 256));  // cnt[N] + flags[256]
  int* offsets = (int*)carve(sizeof(int) * (N + 1));
  int* cursor  = (int*)carve(sizeof(int) * N);
  int* elist   = (int*)carve(sizeof(int) * E);
  int* bsums   = (int*)carve(sizeof(int) * 256);

  int* cnt = cntflags;
  int* flags = cntflags + N;

  const int nbScan = (N + 255) / 256;
  const int nbHist = (E + 255) / 256;
  const int nGemm = (N + BM - 1) / BM;
  const int nEdge = (E + 31) / 32;

  // zero cnt + lookback flags (one memset)
  hipMemsetAsync(cntflags, 0, sizeof(int) * (N + 256), stream);
  // prep: compute_v + tiled weight transpose + hist
  k_prep<<<448 + nbHist, 256, 0, stream>>>(We1, ae1, We2, ae2, v1, v2,
                                           W1, W1t, W2, W2t, dstArr, cnt, E);
  // single-dispatch scan (offsets + cursor)
  k_scan_lb<<<nbScan, 256, 0, stream>>>(cnt, offsets, cursor, bsums, flags, N);

  // fat: GEMM1 (+row-dots, bf16 C) || scatter || edge-alpha (both layers)
  k_fat1<<<nGemm + NSCAT + nEdge, 512, 0, stream>>>(
      x, W1t, xl1b, sArr, dArr, as1, ad1, N,
      edge_attr, v1, v2, ae1Arr, ae2Arr, E, nGemm, dstArr, cursor, elist);
  // layer 1 aggregate (16-lane groups, bf16 gather) -> hb (bf16)
  k_aggregate1<<<(N + 15) / 16, 256, 0, stream>>>(xl1b, sArr, dArr, ae1Arr, srcArr,
                                                  offsets, elist, b1, hb, N);
  // layer 2 GEMM (xl2 bf16, aliases xl1b buffer)
  k_gemm2<<<nGemm, 512, 0, stream>>>(hb, W2t, xl1b, sArr, dArr, as2, ad2, N);
  // fused layer-2 aggregate (pair nodes only, 16-lane groups) + head
  k_agg2head<<<(Bn + 7) / 8, 256, 0, stream>>>(xl1b, sArr, dArr, ae2Arr, srcArr,
                                               offsets, elist, b2, nodes, Wp, bp,
                                               (float*)d_out, Bn);
}